// Round 10
// baseline (196.047 us; speedup 1.0000x reference)
//
#include <hip/hip_runtime.h>

// MultiHeadSelfAttention: B=2, S=2048, E=768, H=12, D=64
// R22: consolidation. (1) flash reverted to R16 verbatim (47.7us verified;
//      five structural variants since all landed 48-62us). (2) gemm2
//      rewritten LDS-free: per-wave A/B MFMA fragments streamed directly
//      from global (Wo^T 1.2MB L2-resident; attn rows read once),
//      reg-double-buffered 1 K-step ahead, zero LDS / zero barriers,
//      unroll-by-2 with named P/N frags. Non-flash portion (~110-125us
//      every round) is now the target. prep/gemmQKV unchanged.

typedef __bf16 bf16_t;
typedef bf16_t bf16x8 __attribute__((ext_vector_type(8)));
typedef bf16_t bf16x4 __attribute__((ext_vector_type(4)));
typedef float f32x4 __attribute__((ext_vector_type(4)));
typedef _Float16 f16x4 __attribute__((ext_vector_type(4)));
typedef _Float16 f16x8 __attribute__((ext_vector_type(8)));
typedef __fp16 hf2 __attribute__((ext_vector_type(2)));

#define SC2 0.1803368801111137f  // 0.125 * log2(e): qk-scale folded into exp2
#define DEFER_THR 44.0f          // ~8/SC2: defer-max rescale threshold (T13)

__device__ __forceinline__ float bf2f(unsigned short u) {
  union { unsigned int i; float f; } x;
  x.i = ((unsigned int)u) << 16;
  return x.f;
}

__device__ __forceinline__ float fexp2(float x) {
  return __builtin_amdgcn_exp2f(x);  // raw v_exp_f32; args <= 8 here, FTZ exact
}

__device__ __forceinline__ void glds16(const bf16_t* g, bf16_t* l) {
  __builtin_amdgcn_global_load_lds(
      (const __attribute__((address_space(1))) void*)g,
      (__attribute__((address_space(3))) void*)l, 16, 0, 0);
}

// dtype probe: wave examines first 1024 u16 words of x. fp32 data => low
// halves carry random mantissa bits => wild bf16 exponents.
__device__ __forceinline__ int detect_bf16_flag(const unsigned short* x) {
  const int lane = threadIdx.x & 63;
  const uint4* p = (const uint4*)x;
  uint4 a = p[lane * 2];
  uint4 b = p[lane * 2 + 1];
  unsigned int w[8] = {a.x, a.y, a.z, a.w, b.x, b.y, b.z, b.w};
  unsigned int big = 0;
#pragma unroll
  for (int i = 0; i < 8; i++) {
    unsigned int e0 = (w[i] >> 7) & 0xFF, e1 = (w[i] >> 23) & 0xFF;
    big |= (e0 > 0x88u) | (e1 > 0x88u);
  }
  unsigned long long bal = __ballot(big != 0u);
  return bal == 0ULL ? 1 : 0;  // 1 => bf16 inputs
}

// ---------------------------------------------------------------- fused prep
__global__ void k_prep(const void* __restrict__ x, const void* __restrict__ mask,
                       const void* __restrict__ Wq, const void* __restrict__ Wk,
                       const void* __restrict__ Wv, const void* __restrict__ Wo,
                       bf16_t* __restrict__ xb, bf16_t* __restrict__ wqkvT,
                       bf16_t* __restrict__ woT, int* __restrict__ mflags) {
  __shared__ float ts[32][33];
  __shared__ int snz;
  const int blk = blockIdx.x;
  const int f = detect_bf16_flag((const unsigned short*)x);

  if (blk < 1536) {  // ---- ingest x (fp32 only; bf16 path reads x directly)
    if (f) return;
    int i = blk * 256 + threadIdx.x;
    const float* xf = (const float*)x + (size_t)i * 8;
    bf16x8 v;
#pragma unroll
    for (int j = 0; j < 8; j++) v[j] = (bf16_t)xf[j];
    *(bf16x8*)(xb + (size_t)i * 8) = v;
  } else if (blk < 3840) {  // ---- W transpose (4 matrices x 24x24 tiles)
    const int t = blk - 1536;
    const int z = t / 576, r = t % 576, kt = r / 24, nt = r % 24;
    const void* wsrc = (z == 0) ? Wq : (z == 1) ? Wk : (z == 2) ? Wv : Wo;
    bf16_t* dst = (z < 3) ? (wqkvT + (size_t)z * 768 * 768) : woT;
    const int c = threadIdx.x & 31, r0 = threadIdx.x >> 5;
#pragma unroll
    for (int i = 0; i < 4; i++) {
      int kr = kt * 32 + r0 + i * 8;
      float v;
      if (f) v = bf2f(((const unsigned short*)wsrc)[(size_t)kr * 768 + nt * 32 + c]);
      else   v = ((const float*)wsrc)[(size_t)kr * 768 + nt * 32 + c];
      ts[r0 + i * 8][c] = v;
    }
    __syncthreads();
#pragma unroll
    for (int i = 0; i < 4; i++) {
      int nr = nt * 32 + r0 + i * 8;
      dst[(size_t)nr * 768 + kt * 32 + c] = (bf16_t)ts[c][r0 + i * 8];
    }
  } else {  // ---- mask nonzero flag per 128x128 tile, uint4 loads
    const int t = blk - 3840;
    const int qt = t >> 4, ktm = t & 15;
    if (threadIdx.x == 0) snz = 0;
    __syncthreads();
    unsigned int nz = 0;
    if (f) {
#pragma unroll
      for (int i = 0; i < 8; i++) {
        int uidx = i * 256 + threadIdx.x;
        int row = uidx >> 4, col = uidx & 15;
        const uint4* p = (const uint4*)((const char*)mask +
            ((size_t)(qt * 128 + row) * 2048 + ktm * 128) * 2 + col * 16);
        uint4 v = *p;
        nz |= ((v.x | v.y | v.z | v.w) & 0x7fff7fffu);
      }
    } else {
#pragma unroll
      for (int i = 0; i < 16; i++) {
        int uidx = i * 256 + threadIdx.x;
        int row = uidx >> 5, col = uidx & 31;
        const uint4* p = (const uint4*)((const char*)mask +
            ((size_t)(qt * 128 + row) * 2048 + ktm * 128) * 4 + col * 16);
        uint4 v = *p;
        nz |= ((v.x | v.y | v.z | v.w) & 0x7fffffffu);
      }
    }
    if (nz) snz = 1;
    __syncthreads();
    if (threadIdx.x == 0) mflags[qt * 16 + ktm] = snz;
  }
}

// ------------------------------------------------------------------ QKV GEMM
// C[4096 x 2304] = A * wqkvT^T, 128x128 tile, BK=32 double-buffered with
// prefetch-before-compute. Epilogues emit flash-ready tiled layouts:
//   Kd: per (b,h,64-key group) 8KB block = permuted-slot LDS image
//   Vt: per (b,h,64-key tile) 8KB block, [64d][128B row ^ ((d&7)<<4)]
__global__ __launch_bounds__(256, 3) void k_gemmQKV(
    const bf16_t* __restrict__ xb, const bf16_t* __restrict__ Bm,
    bf16_t* __restrict__ Qd, char* __restrict__ Kd, char* __restrict__ Vt,
    const unsigned short* __restrict__ xdet) {
  __shared__ __align__(16) char smem[32768];  // A slots @0,8192 | B @16384,24576
  _Float16* Tb = (_Float16*)smem;             // V epilogue reuse (17.4KB)

  const int f = detect_bf16_flag(xdet);
  const bf16_t* A = f ? (const bf16_t*)xdet : xb;

  const int tid = threadIdx.x;
  const int n0 = blockIdx.x * 128, m0 = blockIdx.y * 128;
  const int r = tid >> 2, c8 = (tid & 3) << 3;
  const bf16_t* Ag = A + (size_t)(m0 + r) * 768 + c8;
  const bf16_t* Bg = Bm + (size_t)(n0 + r) * 768 + c8;
  const int wid = tid >> 6, lane = tid & 63;
  const int wm = (wid >> 1) << 6, wn = (wid & 1) << 6;
  const int lr = lane & 15, quad = lane >> 4, lk = quad << 3, g4 = quad << 2;

  f32x4 acc[4][4];
  const f32x4 z = {0.f, 0.f, 0.f, 0.f};
#pragma unroll
  for (int i = 0; i < 4; i++)
#pragma unroll
    for (int j = 0; j < 4; j++) acc[i][j] = z;

  {  // stage k0=0 -> slot 0
    bf16_t* A0 = (bf16_t*)smem;
    bf16_t* B0 = (bf16_t*)(smem + 16384);
    glds16(Ag, A0 + wid * 512);
    glds16(Ag + (size_t)64 * 768, A0 + 2048 + wid * 512);
    glds16(Bg, B0 + wid * 512);
    glds16(Bg + (size_t)64 * 768, B0 + 2048 + wid * 512);
  }
  __syncthreads();

  for (int s = 0; s < 24; s++) {
    if (s < 23) {  // prefetch s+1 into other slot (overlaps compute below)
      const int k0 = (s + 1) * 32;
      bf16_t* An = (bf16_t*)(smem + ((s + 1) & 1) * 8192);
      bf16_t* Bn = (bf16_t*)(smem + 16384 + ((s + 1) & 1) * 8192);
      glds16(Ag + k0, An + wid * 512);
      glds16(Ag + (size_t)64 * 768 + k0, An + 2048 + wid * 512);
      glds16(Bg + k0, Bn + wid * 512);
      glds16(Bg + (size_t)64 * 768 + k0, Bn + 2048 + wid * 512);
    }
    const bf16_t* As = (const bf16_t*)(smem + (s & 1) * 8192);
    const bf16_t* Bs = (const bf16_t*)(smem + 16384 + (s & 1) * 8192);
    bf16x8 af[4], bf_[4];
#pragma unroll
    for (int t = 0; t < 4; t++) af[t]  = *(const bf16x8*)&As[(wm + t * 16 + lr) * 32 + lk];
#pragma unroll
    for (int t = 0; t < 4; t++) bf_[t] = *(const bf16x8*)&Bs[(wn + t * 16 + lr) * 32 + lk];
#pragma unroll
    for (int i = 0; i < 4; i++)
#pragma unroll
      for (int j = 0; j < 4; j++)
        acc[i][j] = __builtin_amdgcn_mfma_f32_16x16x32_bf16(af[i], bf_[j], acc[i][j], 0, 0, 0);
    __syncthreads();  // joins waves + drains this iter's DMA (issued pre-compute)
  }

  if (n0 < 768) {  // Q: natural [seq][d] scatter
    const int bb = m0 >> 11;
#pragma unroll
    for (int i = 0; i < 4; i++)
#pragma unroll
      for (int j = 0; j < 4; j++) {
        const int rc = n0 + wn + j * 16 + lr;
        const int hh = rc >> 6, dd = rc & 63;
        const size_t base = (((size_t)bb * 12 + hh) * 2048) * 64 + dd;
#pragma unroll
        for (int reg = 0; reg < 4; reg++) {
          const int s = (m0 & 2047) + wm + i * 16 + g4 + reg;
          Qd[base + (size_t)s * 64] = (bf16_t)acc[i][j][reg];
        }
      }
  } else if (n0 < 1536) {  // K: permuted-slot tiled layout (flash LDS image)
    const int nb = n0 - 768;
    const int bb = m0 >> 11;
    const int g = ((m0 & 2047) + wm) >> 6;  // 64-key group
#pragma unroll
    for (int i = 0; i < 4; i++) {
#pragma unroll
      for (int j = 0; j < 4; j++) {
        const int rc = nb + wn + j * 16 + lr;
        const int hh = rc >> 6, dd = rc & 63;
        const size_t tbase = ((size_t)((bb * 12 + hh) * 32 + g)) << 13;
        const int doff = ((dd >> 5) << 10) + (((dd >> 3) & 3) << 8) + ((dd & 7) << 1);
#pragma unroll
        for (int reg = 0; reg < 4; reg++) {
          // slot sigma(w), w = 16i + 4*quad + reg (within-64 key index)
          const int sig = ((i >> 1) << 5) + ((quad & 1) << 4) +
                          (((((i & 1) << 1) | (quad >> 1))) << 2) + reg;
          *(bf16_t*)(Kd + tbase + ((sig >> 4) << 11) + ((sig & 15) << 4) + doff) =
              (bf16_t)acc[i][j][reg];
        }
      }
    }
  } else {  // V: LDS transpose -> tiled swizzled [64d][128B^swz] blocks
    const int bb = m0 >> 11;
#pragma unroll
    for (int half = 0; half < 2; half++) {
      if ((wid & 1) == half) {
#pragma unroll
        for (int j = 0; j < 4; j++) {
          const int d_l = j * 16 + lr;
#pragma unroll
          for (int i = 0; i < 4; i++)
#pragma unroll
            for (int reg = 0; reg < 4; reg++)
              Tb[d_l * 136 + wm + i * 16 + g4 + reg] = (_Float16)acc[i][j][reg];
        }
      }
      __syncthreads();
      const int row = tid >> 2, cc = (tid & 3) * 32;  // row = d (0..63)
      const int vcol = (n0 - 1536) + half * 64 + row;
      const int hh = vcol >> 6;
      const int g = ((m0 & 2047) + cc) >> 6;          // 64-key tile
      const int koff2 = (cc & 63) * 2;                // 0 or 64 bytes
      char* vb = Vt + (((size_t)((bb * 12 + hh) * 32 + g)) << 13) + (row << 7);
#pragma unroll
      for (int u = 0; u < 4; u++)
        *(uint4*)(vb + ((koff2 + u * 16) ^ ((row & 7) << 4))) =
            *(const uint4*)&Tb[row * 136 + cc + u * 8];
      __syncthreads();
    }
  }
}

// ----------------------------------------------------------- flash attention
// R16 verbatim (47.7us verified): 768 blocks x 256 thr, 4 compute waves, no
// producer. K/V tiles contiguous 8KB global blocks (pre-permuted/swizzled),
// staged via global_load_lds; software-pipelined: iter s issues QK(s+1)
// before softmax(s)+PV(s); K staged 2 ahead, V 1 ahead. 1 barrier/iter.
__global__ __launch_bounds__(256, 3) void k_flash(
    const bf16_t* __restrict__ Qd, const char* __restrict__ Kd,
    const char* __restrict__ Vt, const void* __restrict__ mask,
    const int* __restrict__ mflags, const unsigned short* __restrict__ xdet,
    bf16_t* __restrict__ attn) {
  __shared__ __align__(16) char sm[32768];

  const int tid = threadIdx.x, wid = tid >> 6, lane = tid & 63;
  const int lr = lane & 15, quad = lane >> 4, lk = quad << 3, g4 = quad << 2;

  const int lin = blockIdx.x;
  const int gx = lin & 7, ww = lin >> 3;
  const int hb = gx * 3 + (ww >> 5);
  const int h = hb % 12, bb = hb / 12;
  const int qt = ww & 31;

  const size_t bh = (size_t)bb * 12 + h;
  const char* Kg = Kd + (bh << 18);  // 32 tiles x 8KB = 256KB per (b,h)
  const char* Vg = Vt + (bh << 18);

  const char* kgl = Kg + wid * 2048 + lane * 16;
  const char* vgl = Vg + wid * 2048 + lane * 16;

#define STAGE_K(t, p)                                                       \
  {                                                                         \
    const char* g_ = kgl + ((size_t)(t) << 13);                             \
    bf16_t* l_ = (bf16_t*)(sm + ((p) << 13) + wid * 2048);                  \
    glds16((const bf16_t*)g_, l_);                                          \
    glds16((const bf16_t*)(g_ + 1024), l_ + 512);                           \
  }
#define STAGE_V(t, p)                                                       \
  {                                                                         \
    const char* g_ = vgl + ((size_t)(t) << 13);                             \
    bf16_t* l_ = (bf16_t*)(sm + 16384 + ((p) << 13) + wid * 2048);          \
    glds16((const bf16_t*)g_, l_);                                          \
    glds16((const bf16_t*)(g_ + 1024), l_ + 512);                           \
  }

  STAGE_K(0, 0);
  STAGE_V(0, 0);
  STAGE_K(1, 1);

  const bf16_t* Qh = Qd + bh * 2048 * 64;
  const int q0 = qt * 64 + wid * 16;
  const int mbf = detect_bf16_flag(xdet);
  const int* mfrow = mflags + (qt >> 1) * 16;
  int mbits = 0;
#pragma unroll
  for (int t = 0; t < 16; t++) mbits |= (mfrow[t] != 0) << t;

  const bf16x8 qf0 = *(const bf16x8*)&Qh[(size_t)(q0 + lr) * 64 + lk];
  const bf16x8 qf1 = *(const bf16x8*)&Qh[(size_t)(q0 + lr) * 64 + 32 + lk];

  f16x8 ones8;
#pragma unroll
  for (int j = 0; j < 8; j++) ones8[j] = (_Float16)1.f;

  // V read offsets (per-lane constant): row = dt*16+lr, chunk XOR by (lr&7)
  const int vxo0 = (quad * 16) ^ ((lr & 7) << 4);
  const int vxo1 = (64 + quad * 16) ^ ((lr & 7) << 4);

  const f32x4 z = {0.f, 0.f, 0.f, 0.f};
  f32x4 ot[4];
#pragma unroll
  for (int dt = 0; dt < 4; dt++) ot[dt] = z;
  float mrow = -1e30f, lrow = 0.f;

  __syncthreads();  // drains K0/V0/K1 DMA, joins waves

  f32x4 svA[4], svB[4];
  {  // prologue: QK_0 -> svA (reads KB0)
#pragma unroll
    for (int ct = 0; ct < 4; ct++) svA[ct] = z;
#pragma unroll
    for (int ct = 0; ct < 4; ct++) {
      bf16x8 kf0 = *(const bf16x8*)(sm + ct * 2048 + lane * 16);
      bf16x8 kf1 = *(const bf16x8*)(sm + ct * 2048 + 1024 + lane * 16);
      svA[ct] = __builtin_amdgcn_mfma_f32_16x16x32_bf16(kf0, qf0, svA[ct], 0, 0, 0);
      svA[ct] = __builtin_amdgcn_mfma_f32_16x16x32_bf16(kf1, qf1, svA[ct], 0, 0, 0);
    }
  }
  __syncthreads();  // protect KB0 from body-0's restage (K_2)

  // BODY(s): stage K_{s+2}/V_{s+1}; QK_{s+1}->SVN; mask/softmax/PV on SVC.
#define FLASH_BODY(S, SVC, SVN)                                              \
  {                                                                          \
    const int s_ = (S);                                                      \
    if (s_ + 2 < 32) STAGE_K(s_ + 2, (s_) & 1);                              \
    if (s_ + 1 < 32) STAGE_V(s_ + 1, (s_ + 1) & 1);                          \
    if (s_ + 1 < 32) {                                                       \
      const char* Kn = sm + (((s_ + 1) & 1) << 13);                          \
      SVN[0] = z; SVN[1] = z; SVN[2] = z; SVN[3] = z;                        \
      __builtin_amdgcn_s_setprio(1);                                         \
      _Pragma("unroll")                                                      \
      for (int ct = 0; ct < 4; ct++) {                                       \
        bf16x8 kf0 = *(const bf16x8*)(Kn + ct * 2048 + lane * 16);           \
        bf16x8 kf1 = *(const bf16x8*)(Kn + ct * 2048 + 1024 + lane * 16);    \
        SVN[ct] = __builtin_amdgcn_mfma_f32_16x16x32_bf16(kf0, qf0, SVN[ct], 0, 0, 0); \
        SVN[ct] = __builtin_amdgcn_mfma_f32_16x16x32_bf16(kf1, qf1, SVN[ct], 0, 0, 0); \
      }                                                                      \
      __builtin_amdgcn_s_setprio(0);                                         \
    }                                                                        \
    if ((mbits >> (s_ >> 1)) & 1) {                                          \
      _Pragma("unroll")                                                      \
      for (int ct = 0; ct < 4; ct++) {                                       \
        _Pragma("unroll")                                                    \
        for (int reg = 0; reg < 4; reg++) {                                  \
          const int kk = ((ct >> 1) << 5) + (quad << 3) + ((ct & 1) << 2) + reg; \
          size_t mi = (size_t)(q0 + lr) * 2048 + s_ * 64 + kk;               \
          float mv = mbf ? bf2f(((const unsigned short*)mask)[mi])           \
                         : ((const float*)mask)[mi];                         \
          SVC[ct][reg] -= 8e9f * mv;                                         \
        }                                                                    \
      }                                                                      \
    }                                                                        \
    float t_ = fmaxf(                                                        \
        fmaxf(fmaxf(fmaxf(SVC[0][0], SVC[0][1]), fmaxf(SVC[0][2], SVC[0][3])), \
              fmaxf(fmaxf(SVC[1][0], SVC[1][1]), fmaxf(SVC[1][2], SVC[1][3]))), \
        fmaxf(fmaxf(fmaxf(SVC[2][0], SVC[2][1]), fmaxf(SVC[2][2], SVC[2][3])), \
              fmaxf(fmaxf(SVC[3][0], SVC[3][1]), fmaxf(SVC[3][2], SVC[3][3])))); \
    t_ = fmaxf(t_, __shfl_xor(t_, 16));                                      \
    t_ = fmaxf(t_, __shfl_xor(t_, 32));                                      \
    if (__ballot(t_ > mrow + DEFER_THR)) {                                   \
      const float mnew = fmaxf(mrow, t_);                                    \
      const float alpha = fexp2((mrow - mnew) * SC2);                        \
      _Pragma("unroll")                                                      \
      for (int dt = 0; dt < 4; dt++) {                                       \
        _Pragma("unroll")                                                    \
        for (int reg = 0; reg < 4; reg++) ot[dt][reg] *= alpha;              \
      }                                                                      \
      lrow *= alpha;                                                         \
      mrow = mnew;                                                           \
    }                                                                        \
    const float mS = mrow * SC2;                                             \
    f16x8 pb8[2];                                                            \
    _Pragma("unroll")                                                        \
    for (int c2 = 0; c2 < 2; c2++) {                                         \
      union { hf2 hh[4]; f16x8 v; } u;                                       \
      _Pragma("unroll")                                                      \
      for (int hh2 = 0; hh2 < 2; hh2++) {                                    \
        const int ct = c2 * 2 + hh2;                                         \
        float p0 = fexp2(fmaf(SVC[ct][0], SC2, -mS));                        \
        float p1 = fexp2(fmaf(SVC[ct][1], SC2, -mS));                        \
        float p2 = fexp2(fmaf(SVC[ct][2], SC2, -mS));                        \
        float p3 = fexp2(fmaf(SVC[ct][3], SC2, -mS));                        \
        u.hh[hh2 * 2 + 0] = __builtin_amdgcn_cvt_pkrtz(p0, p1);              \
        u.hh[hh2 * 2 + 1] = __builtin_amdgcn_cvt_pkrtz(p2, p3);              \
      }                                                                      \
      pb8[c2] = u.v;                                                         \
    }                                                                        \
    const char* Vc = sm + 16384 + ((s_ & 1) << 13);                          \
    f32x4 asum = z;                                                          \
    __builtin_amdgcn_s_setprio(1);                                           \
    _Pragma("unroll")                                                        \
    for (int c2 = 0; c2 < 2; c2++) {                                         \
      const int vxo = c2 ? vxo1 : vxo0;                                      \
      asum = __builtin_amdgcn_mfma_f32_16x16x32_f16(ones8, pb8[c2], asum, 0, 0, 0); \
      _Pragma("unroll")                                                      \
      for (int dt = 0; dt < 4; dt++) {                                       \
        f16x8 va = *(const f16x8*)(Vc + (dt * 16 + lr) * 128 + vxo);         \
        ot[dt] = __builtin_amdgcn_mfma_f32_16x16x32_f16(va, pb8[c2], ot[dt], 0, 0, 0); \
      }                                                                      \
    }                                                                        \
    __builtin_amdgcn_s_setprio(0);                                           \
    lrow += asum[0];                                                         \
    if (s_ < 31) __syncthreads();                                            \
  }

  for (int s2 = 0; s2 < 32; s2 += 2) {
    FLASH_BODY(s2, svA, svB);
    FLASH_BODY(s2 + 1, svB, svA);
  }
#undef FLASH_BODY
#undef STAGE_K
#undef STAGE_V

  const float inv = 1.0f / lrow;
  bf16_t* arow = attn + ((size_t)bb * 2048 + q0 + lr) * 768 + h * 64 + g4;
#pragma unroll
  for (int dt = 0; dt < 4; dt++) {
    bf16x4 v;
#pragma unroll
    for (int reg = 0; reg < 4; reg++) v[reg] = (bf16_t)(ot[dt][reg] * inv);
    *(bf16x4*)(arow + dt * 16) = v;
  }
}

// -------------------------------------------------- output GEMM (attn @ Wo^T)
// R22: LDS-free fragment streaming. 64x64 tiles -> 768 blocks (256 thr,
// 4 waves, each 32x32 output). A/B MFMA fragments read directly from global
// (Wo^T 1.2MB L2-resident; attn read once), reg-double-buffered 1 K-step
// ahead, zero LDS / zero barriers. Unroll-by-2 with named P/N frags.
__global__ __launch_bounds__(256, 2) void k_gemm2(
    const bf16_t* __restrict__ A, const bf16_t* __restrict__ Bm,
    const void* __restrict__ bo, const unsigned short* __restrict__ xdet,
    float* __restrict__ outF, unsigned short* __restrict__ outH) {
  const int tid = threadIdx.x, wid = tid >> 6, lane = tid & 63;
  const int n0 = blockIdx.x * 64, m0 = blockIdx.y * 64;
  const int wm = (wid >> 1) << 5, wn = (wid & 1) << 5;
  const int lr = lane & 15, lk = (lane >> 4) << 3, g4 = (lane >> 4) << 2;

  // fragment base pointers (row fixed per lane, col walks k)
  const bf16_t* A0 = A  + (size_t)(m0 + wm + lr) * 768 + lk;
  const bf16_t* A1 = A  + (size_t)(m0 + wm + 16 + lr) * 768 + lk;
  const bf16_t* B0 = Bm + (size_t)(n0 + wn + lr) * 768 + lk;
  const bf16_t* B1 = Bm + (size_t)(n0 + wn + 16 + lr) * 768 + lk;

  f32x4 acc[2][2];
  const f32x4 z = {0.f, 0.f, 0.f, 0.f};
#pragma unroll
  for (int i = 0; i < 2; i++)
#pragma unroll
    for (int j = 0; j < 2; j++) acc[i][j] = z;

  bf16x8 aP[2], bP[2], aN[2], bN[2];
  aP[0] = *(const bf16x8*)A0;
  aP[1] = *(const bf16x8*)A1;
  bP[0] = *(const bf16x8*)B0;
  bP[1] = *(const bf16x8*)B1;

#define G2_BODY(S, AC, BC, AX, BX)                                           \
  {                                                                          \
    const int s_ = (S);                                                      \
    if (s_ + 1 < 24) {                                                       \
      const int k1 = (s_ + 1) * 32;                                          \
      AX[0] = *(const bf16x8*)(A0 + k1);                                     \
      AX[1] = *(const bf16x8*)(A1 + k1);                                     \
      BX[0] = *(const bf16x8*)(B0 + k1);                                     \
      BX[1] = *(const bf16x8*)(B1 + k1);                                     \
    }                                                                        \
    _Pragma("unroll")                                                        \
    for (int i = 0; i < 2; i++) {                                            \
      _Pragma("unroll")                                                      \
      for (int j = 0; j < 2; j++)                                            \
        acc[i][j] = __builtin_amdgcn_mfma_f32_16x16x32_bf16(AC[i], BC[j],    \
                                                            acc[i][j], 0, 0, 0); \
    }                                                                        \
  }

  for (int s2 = 0; s2 < 24; s2 += 2) {
    G2_BODY(s2, aP, bP, aN, bN);
    G2_BODY(s2 + 1, aN, bN, aP, bP);
  }
#undef G2_BODY

  const int obf = detect_bf16_flag(xdet);
#pragma unroll
  for (int i = 0; i < 2; i++)
#pragma unroll
    for (int j = 0; j < 2; j++) {
      const int nn = n0 + wn + j * 16 + lr;
      const float bv = obf ? bf2f(((const unsigned short*)bo)[nn])
                           : ((const float*)bo)[nn];
#pragma unroll
      for (int reg = 0; reg < 4; reg++) {
        const int m = m0 + wm + i * 16 + g4 + reg;
        const float v = acc[i][j][reg] + bv;
        if (obf) outH[(size_t)m * 768 + nn] = __builtin_bit_cast(unsigned short, (bf16_t)v);
        else     outF[(size_t)m * 768 + nn] = v;
      }
    }
}

// -------------------------------------------------------------------- launch
extern "C" void kernel_launch(void* const* d_in, const int* in_sizes, int n_in,
                              void* d_out, int out_size, void* d_ws, size_t ws_size,
                              hipStream_t stream) {
  (void)in_sizes; (void)n_in; (void)out_size; (void)ws_size;
  const void* x    = d_in[0];
  const void* mask = d_in[1];
  const void* Wq   = d_in[2];
  const void* Wk   = d_in[3];
  const void* Wv   = d_in[4];
  const void* Wo   = d_in[5];
  const void* bo   = d_in[6];

  char* w = (char*)d_ws;
  size_t off = 0;
  auto take = [&](size_t b) -> void* {
    void* p = w + off;
    off = (off + b + 255) & ~(size_t)255;
    return p;
  };
  int*      mflags = (int*)take(256 * 4);
  bf16_t*   wqkvT  = (bf16_t*)take((size_t)2304 * 768 * 2);
  bf16_t*   woT    = (bf16_t*)take((size_t)768 * 768 * 2);
  bf16_t*   xb     = (bf16_t*)take((size_t)4096 * 768 * 2);
  bf16_t*   Qd     = (bf16_t*)take((size_t)3145728 * 2);
  char*     Kd     = (char*)take((size_t)3145728 * 2);
  char*     Vt     = (char*)take((size_t)3145728 * 2);
  bf16_t*   attn   = xb;  // xb dead after QKV GEMM (flash output reuses it)

  k_prep<<<4096, 256, 0, stream>>>(x, mask, Wq, Wk, Wv, Wo, xb, wqkvT, woT, mflags);
  k_gemmQKV<<<dim3(18, 32), 256, 0, stream>>>(xb, wqkvT, Qd, Kd, Vt,
                                              (const unsigned short*)x);
  k_flash<<<768, 256, 0, stream>>>(Qd, Kd, Vt, mask, mflags,
                                   (const unsigned short*)x, attn);
  k_gemm2<<<dim3(12, 64), 256, 0, stream>>>(attn, woT, bo, (const unsigned short*)x,
                                            (float*)d_out, (unsigned short*)d_out);
}

// Round 12
// 168.536 us; speedup vs baseline: 1.1632x; 1.1632x over previous
//
#include <hip/hip_runtime.h>

// MultiHeadSelfAttention: B=2, S=2048, E=768, H=12, D=64
// R24: identical resubmit of R23 — previous bench failed on infra
//      (container), no counters. R23 = (1) gemm2 reverted to verified LDS
//      version (R22's LDS-free was -23us), (2) T1 XCD-aware block swizzle
//      on gemmQKV (576 blocks, chunk=72) and gemm2 (768 blocks, chunk=96).
//      flash = R16 verbatim (47.7us verified). prep unchanged.

typedef __bf16 bf16_t;
typedef bf16_t bf16x8 __attribute__((ext_vector_type(8)));
typedef bf16_t bf16x4 __attribute__((ext_vector_type(4)));
typedef float f32x4 __attribute__((ext_vector_type(4)));
typedef _Float16 f16x4 __attribute__((ext_vector_type(4)));
typedef _Float16 f16x8 __attribute__((ext_vector_type(8)));
typedef __fp16 hf2 __attribute__((ext_vector_type(2)));

#define SC2 0.1803368801111137f  // 0.125 * log2(e): qk-scale folded into exp2
#define DEFER_THR 44.0f          // ~8/SC2: defer-max rescale threshold (T13)

__device__ __forceinline__ float bf2f(unsigned short u) {
  union { unsigned int i; float f; } x;
  x.i = ((unsigned int)u) << 16;
  return x.f;
}

__device__ __forceinline__ float fexp2(float x) {
  return __builtin_amdgcn_exp2f(x);  // raw v_exp_f32; args <= 8 here, FTZ exact
}

__device__ __forceinline__ void glds16(const bf16_t* g, bf16_t* l) {
  __builtin_amdgcn_global_load_lds(
      (const __attribute__((address_space(1))) void*)g,
      (__attribute__((address_space(3))) void*)l, 16, 0, 0);
}

// dtype probe: wave examines first 1024 u16 words of x. fp32 data => low
// halves carry random mantissa bits => wild bf16 exponents.
__device__ __forceinline__ int detect_bf16_flag(const unsigned short* x) {
  const int lane = threadIdx.x & 63;
  const uint4* p = (const uint4*)x;
  uint4 a = p[lane * 2];
  uint4 b = p[lane * 2 + 1];
  unsigned int w[8] = {a.x, a.y, a.z, a.w, b.x, b.y, b.z, b.w};
  unsigned int big = 0;
#pragma unroll
  for (int i = 0; i < 8; i++) {
    unsigned int e0 = (w[i] >> 7) & 0xFF, e1 = (w[i] >> 23) & 0xFF;
    big |= (e0 > 0x88u) | (e1 > 0x88u);
  }
  unsigned long long bal = __ballot(big != 0u);
  return bal == 0ULL ? 1 : 0;  // 1 => bf16 inputs
}

// ---------------------------------------------------------------- fused prep
__global__ void k_prep(const void* __restrict__ x, const void* __restrict__ mask,
                       const void* __restrict__ Wq, const void* __restrict__ Wk,
                       const void* __restrict__ Wv, const void* __restrict__ Wo,
                       bf16_t* __restrict__ xb, bf16_t* __restrict__ wqkvT,
                       bf16_t* __restrict__ woT, int* __restrict__ mflags) {
  __shared__ float ts[32][33];
  __shared__ int snz;
  const int blk = blockIdx.x;
  const int f = detect_bf16_flag((const unsigned short*)x);

  if (blk < 1536) {  // ---- ingest x (fp32 only; bf16 path reads x directly)
    if (f) return;
    int i = blk * 256 + threadIdx.x;
    const float* xf = (const float*)x + (size_t)i * 8;
    bf16x8 v;
#pragma unroll
    for (int j = 0; j < 8; j++) v[j] = (bf16_t)xf[j];
    *(bf16x8*)(xb + (size_t)i * 8) = v;
  } else if (blk < 3840) {  // ---- W transpose (4 matrices x 24x24 tiles)
    const int t = blk - 1536;
    const int z = t / 576, r = t % 576, kt = r / 24, nt = r % 24;
    const void* wsrc = (z == 0) ? Wq : (z == 1) ? Wk : (z == 2) ? Wv : Wo;
    bf16_t* dst = (z < 3) ? (wqkvT + (size_t)z * 768 * 768) : woT;
    const int c = threadIdx.x & 31, r0 = threadIdx.x >> 5;
#pragma unroll
    for (int i = 0; i < 4; i++) {
      int kr = kt * 32 + r0 + i * 8;
      float v;
      if (f) v = bf2f(((const unsigned short*)wsrc)[(size_t)kr * 768 + nt * 32 + c]);
      else   v = ((const float*)wsrc)[(size_t)kr * 768 + nt * 32 + c];
      ts[r0 + i * 8][c] = v;
    }
    __syncthreads();
#pragma unroll
    for (int i = 0; i < 4; i++) {
      int nr = nt * 32 + r0 + i * 8;
      dst[(size_t)nr * 768 + kt * 32 + c] = (bf16_t)ts[c][r0 + i * 8];
    }
  } else {  // ---- mask nonzero flag per 128x128 tile, uint4 loads
    const int t = blk - 3840;
    const int qt = t >> 4, ktm = t & 15;
    if (threadIdx.x == 0) snz = 0;
    __syncthreads();
    unsigned int nz = 0;
    if (f) {
#pragma unroll
      for (int i = 0; i < 8; i++) {
        int uidx = i * 256 + threadIdx.x;
        int row = uidx >> 4, col = uidx & 15;
        const uint4* p = (const uint4*)((const char*)mask +
            ((size_t)(qt * 128 + row) * 2048 + ktm * 128) * 2 + col * 16);
        uint4 v = *p;
        nz |= ((v.x | v.y | v.z | v.w) & 0x7fff7fffu);
      }
    } else {
#pragma unroll
      for (int i = 0; i < 16; i++) {
        int uidx = i * 256 + threadIdx.x;
        int row = uidx >> 5, col = uidx & 31;
        const uint4* p = (const uint4*)((const char*)mask +
            ((size_t)(qt * 128 + row) * 2048 + ktm * 128) * 4 + col * 16);
        uint4 v = *p;
        nz |= ((v.x | v.y | v.z | v.w) & 0x7fffffffu);
      }
    }
    if (nz) snz = 1;
    __syncthreads();
    if (threadIdx.x == 0) mflags[qt * 16 + ktm] = snz;
  }
}

// ------------------------------------------------------------------ QKV GEMM
// C[4096 x 2304] = A * wqkvT^T, 128x128 tile, BK=32 double-buffered with
// prefetch-before-compute. XCD-swizzled tile assignment (T1): each XCD gets
// a contiguous chunk of 72 tiles (4 m-panels x 18 n) -> A-panels + B-panels
// fit its 4MB L2; A fetched from HBM once. Epilogues emit flash-ready
// layouts: Kd permuted-slot 8KB tiles, Vt swizzled [64d][128B^swz] tiles.
__global__ __launch_bounds__(256, 3) void k_gemmQKV(
    const bf16_t* __restrict__ xb, const bf16_t* __restrict__ Bm,
    bf16_t* __restrict__ Qd, char* __restrict__ Kd, char* __restrict__ Vt,
    const unsigned short* __restrict__ xdet) {
  __shared__ __align__(16) char smem[32768];  // A slots @0,8192 | B @16384,24576
  _Float16* Tb = (_Float16*)smem;             // V epilogue reuse (17.4KB)

  const int f = detect_bf16_flag(xdet);
  const bf16_t* A = f ? (const bf16_t*)xdet : xb;

  const int tid = threadIdx.x;
  // T1 XCD swizzle: 576 blocks, chunk=72/XCD (bijective, 576%8==0)
  const int lin = blockIdx.y * 18 + blockIdx.x;
  const int sw = (lin & 7) * 72 + (lin >> 3);
  const int n0 = (sw % 18) * 128, m0 = (sw / 18) * 128;
  const int r = tid >> 2, c8 = (tid & 3) << 3;
  const bf16_t* Ag = A + (size_t)(m0 + r) * 768 + c8;
  const bf16_t* Bg = Bm + (size_t)(n0 + r) * 768 + c8;
  const int wid = tid >> 6, lane = tid & 63;
  const int wm = (wid >> 1) << 6, wn = (wid & 1) << 6;
  const int lr = lane & 15, quad = lane >> 4, lk = quad << 3, g4 = quad << 2;

  f32x4 acc[4][4];
  const f32x4 z = {0.f, 0.f, 0.f, 0.f};
#pragma unroll
  for (int i = 0; i < 4; i++)
#pragma unroll
    for (int j = 0; j < 4; j++) acc[i][j] = z;

  {  // stage k0=0 -> slot 0
    bf16_t* A0 = (bf16_t*)smem;
    bf16_t* B0 = (bf16_t*)(smem + 16384);
    glds16(Ag, A0 + wid * 512);
    glds16(Ag + (size_t)64 * 768, A0 + 2048 + wid * 512);
    glds16(Bg, B0 + wid * 512);
    glds16(Bg + (size_t)64 * 768, B0 + 2048 + wid * 512);
  }
  __syncthreads();

  for (int s = 0; s < 24; s++) {
    if (s < 23) {  // prefetch s+1 into other slot (overlaps compute below)
      const int k0 = (s + 1) * 32;
      bf16_t* An = (bf16_t*)(smem + ((s + 1) & 1) * 8192);
      bf16_t* Bn = (bf16_t*)(smem + 16384 + ((s + 1) & 1) * 8192);
      glds16(Ag + k0, An + wid * 512);
      glds16(Ag + (size_t)64 * 768 + k0, An + 2048 + wid * 512);
      glds16(Bg + k0, Bn + wid * 512);
      glds16(Bg + (size_t)64 * 768 + k0, Bn + 2048 + wid * 512);
    }
    const bf16_t* As = (const bf16_t*)(smem + (s & 1) * 8192);
    const bf16_t* Bs = (const bf16_t*)(smem + 16384 + (s & 1) * 8192);
    bf16x8 af[4], bf_[4];
#pragma unroll
    for (int t = 0; t < 4; t++) af[t]  = *(const bf16x8*)&As[(wm + t * 16 + lr) * 32 + lk];
#pragma unroll
    for (int t = 0; t < 4; t++) bf_[t] = *(const bf16x8*)&Bs[(wn + t * 16 + lr) * 32 + lk];
#pragma unroll
    for (int i = 0; i < 4; i++)
#pragma unroll
      for (int j = 0; j < 4; j++)
        acc[i][j] = __builtin_amdgcn_mfma_f32_16x16x32_bf16(af[i], bf_[j], acc[i][j], 0, 0, 0);
    __syncthreads();  // joins waves + drains this iter's DMA (issued pre-compute)
  }

  if (n0 < 768) {  // Q: natural [seq][d] scatter
    const int bb = m0 >> 11;
#pragma unroll
    for (int i = 0; i < 4; i++)
#pragma unroll
      for (int j = 0; j < 4; j++) {
        const int rc = n0 + wn + j * 16 + lr;
        const int hh = rc >> 6, dd = rc & 63;
        const size_t base = (((size_t)bb * 12 + hh) * 2048) * 64 + dd;
#pragma unroll
        for (int reg = 0; reg < 4; reg++) {
          const int s = (m0 & 2047) + wm + i * 16 + g4 + reg;
          Qd[base + (size_t)s * 64] = (bf16_t)acc[i][j][reg];
        }
      }
  } else if (n0 < 1536) {  // K: permuted-slot tiled layout (flash LDS image)
    const int nb = n0 - 768;
    const int bb = m0 >> 11;
    const int g = ((m0 & 2047) + wm) >> 6;  // 64-key group
#pragma unroll
    for (int i = 0; i < 4; i++) {
#pragma unroll
      for (int j = 0; j < 4; j++) {
        const int rc = nb + wn + j * 16 + lr;
        const int hh = rc >> 6, dd = rc & 63;
        const size_t tbase = ((size_t)((bb * 12 + hh) * 32 + g)) << 13;
        const int doff = ((dd >> 5) << 10) + (((dd >> 3) & 3) << 8) + ((dd & 7) << 1);
#pragma unroll
        for (int reg = 0; reg < 4; reg++) {
          // slot sigma(w), w = 16i + 4*quad + reg (within-64 key index)
          const int sig = ((i >> 1) << 5) + ((quad & 1) << 4) +
                          (((((i & 1) << 1) | (quad >> 1))) << 2) + reg;
          *(bf16_t*)(Kd + tbase + ((sig >> 4) << 11) + ((sig & 15) << 4) + doff) =
              (bf16_t)acc[i][j][reg];
        }
      }
    }
  } else {  // V: LDS transpose -> tiled swizzled [64d][128B^swz] blocks
    const int bb = m0 >> 11;
#pragma unroll
    for (int half = 0; half < 2; half++) {
      if ((wid & 1) == half) {
#pragma unroll
        for (int j = 0; j < 4; j++) {
          const int d_l = j * 16 + lr;
#pragma unroll
          for (int i = 0; i < 4; i++)
#pragma unroll
            for (int reg = 0; reg < 4; reg++)
              Tb[d_l * 136 + wm + i * 16 + g4 + reg] = (_Float16)acc[i][j][reg];
        }
      }
      __syncthreads();
      const int row = tid >> 2, cc = (tid & 3) * 32;  // row = d (0..63)
      const int vcol = (n0 - 1536) + half * 64 + row;
      const int hh = vcol >> 6;
      const int g = ((m0 & 2047) + cc) >> 6;          // 64-key tile
      const int koff2 = (cc & 63) * 2;                // 0 or 64 bytes
      char* vb = Vt + (((size_t)((bb * 12 + hh) * 32 + g)) << 13) + (row << 7);
#pragma unroll
      for (int u = 0; u < 4; u++)
        *(uint4*)(vb + ((koff2 + u * 16) ^ ((row & 7) << 4))) =
            *(const uint4*)&Tb[row * 136 + cc + u * 8];
      __syncthreads();
    }
  }
}

// ----------------------------------------------------------- flash attention
// R16 verbatim (47.7us verified): 768 blocks x 256 thr, 4 compute waves, no
// producer. K/V tiles contiguous 8KB global blocks (pre-permuted/swizzled),
// staged via global_load_lds; software-pipelined: iter s issues QK(s+1)
// before softmax(s)+PV(s); K staged 2 ahead, V 1 ahead. 1 barrier/iter.
__global__ __launch_bounds__(256, 3) void k_flash(
    const bf16_t* __restrict__ Qd, const char* __restrict__ Kd,
    const char* __restrict__ Vt, const void* __restrict__ mask,
    const int* __restrict__ mflags, const unsigned short* __restrict__ xdet,
    bf16_t* __restrict__ attn) {
  __shared__ __align__(16) char sm[32768];

  const int tid = threadIdx.x, wid = tid >> 6, lane = tid & 63;
  const int lr = lane & 15, quad = lane >> 4, lk = quad << 3, g4 = quad << 2;

  const int lin = blockIdx.x;
  const int gx = lin & 7, ww = lin >> 3;
  const int hb = gx * 3 + (ww >> 5);
  const int h = hb % 12, bb = hb / 12;
  const int qt = ww & 31;

  const size_t bh = (size_t)bb * 12 + h;
  const char* Kg = Kd + (bh << 18);  // 32 tiles x 8KB = 256KB per (b,h)
  const char* Vg = Vt + (bh << 18);

  const char* kgl = Kg + wid * 2048 + lane * 16;
  const char* vgl = Vg + wid * 2048 + lane * 16;

#define STAGE_K(t, p)                                                       \
  {                                                                         \
    const char* g_ = kgl + ((size_t)(t) << 13);                             \
    bf16_t* l_ = (bf16_t*)(sm + ((p) << 13) + wid * 2048);                  \
    glds16((const bf16_t*)g_, l_);                                          \
    glds16((const bf16_t*)(g_ + 1024), l_ + 512);                           \
  }
#define STAGE_V(t, p)                                                       \
  {                                                                         \
    const char* g_ = vgl + ((size_t)(t) << 13);                             \
    bf16_t* l_ = (bf16_t*)(sm + 16384 + ((p) << 13) + wid * 2048);          \
    glds16((const bf16_t*)g_, l_);                                          \
    glds16((const bf16_t*)(g_ + 1024), l_ + 512);                           \
  }

  STAGE_K(0, 0);
  STAGE_V(0, 0);
  STAGE_K(1, 1);

  const bf16_t* Qh = Qd + bh * 2048 * 64;
  const int q0 = qt * 64 + wid * 16;
  const int mbf = detect_bf16_flag(xdet);
  const int* mfrow = mflags + (qt >> 1) * 16;
  int mbits = 0;
#pragma unroll
  for (int t = 0; t < 16; t++) mbits |= (mfrow[t] != 0) << t;

  const bf16x8 qf0 = *(const bf16x8*)&Qh[(size_t)(q0 + lr) * 64 + lk];
  const bf16x8 qf1 = *(const bf16x8*)&Qh[(size_t)(q0 + lr) * 64 + 32 + lk];

  f16x8 ones8;
#pragma unroll
  for (int j = 0; j < 8; j++) ones8[j] = (_Float16)1.f;

  // V read offsets (per-lane constant): row = dt*16+lr, chunk XOR by (lr&7)
  const int vxo0 = (quad * 16) ^ ((lr & 7) << 4);
  const int vxo1 = (64 + quad * 16) ^ ((lr & 7) << 4);

  const f32x4 z = {0.f, 0.f, 0.f, 0.f};
  f32x4 ot[4];
#pragma unroll
  for (int dt = 0; dt < 4; dt++) ot[dt] = z;
  float mrow = -1e30f, lrow = 0.f;

  __syncthreads();  // drains K0/V0/K1 DMA, joins waves

  f32x4 svA[4], svB[4];
  {  // prologue: QK_0 -> svA (reads KB0)
#pragma unroll
    for (int ct = 0; ct < 4; ct++) svA[ct] = z;
#pragma unroll
    for (int ct = 0; ct < 4; ct++) {
      bf16x8 kf0 = *(const bf16x8*)(sm + ct * 2048 + lane * 16);
      bf16x8 kf1 = *(const bf16x8*)(sm + ct * 2048 + 1024 + lane * 16);
      svA[ct] = __builtin_amdgcn_mfma_f32_16x16x32_bf16(kf0, qf0, svA[ct], 0, 0, 0);
      svA[ct] = __builtin_amdgcn_mfma_f32_16x16x32_bf16(kf1, qf1, svA[ct], 0, 0, 0);
    }
  }
  __syncthreads();  // protect KB0 from body-0's restage (K_2)

  // BODY(s): stage K_{s+2}/V_{s+1}; QK_{s+1}->SVN; mask/softmax/PV on SVC.
#define FLASH_BODY(S, SVC, SVN)                                              \
  {                                                                          \
    const int s_ = (S);                                                      \
    if (s_ + 2 < 32) STAGE_K(s_ + 2, (s_) & 1);                              \
    if (s_ + 1 < 32) STAGE_V(s_ + 1, (s_ + 1) & 1);                          \
    if (s_ + 1 < 32) {                                                       \
      const char* Kn = sm + (((s_ + 1) & 1) << 13);                          \
      SVN[0] = z; SVN[1] = z; SVN[2] = z; SVN[3] = z;                        \
      __builtin_amdgcn_s_setprio(1);                                         \
      _Pragma("unroll")                                                      \
      for (int ct = 0; ct < 4; ct++) {                                       \
        bf16x8 kf0 = *(const bf16x8*)(Kn + ct * 2048 + lane * 16);           \
        bf16x8 kf1 = *(const bf16x8*)(Kn + ct * 2048 + 1024 + lane * 16);    \
        SVN[ct] = __builtin_amdgcn_mfma_f32_16x16x32_bf16(kf0, qf0, SVN[ct], 0, 0, 0); \
        SVN[ct] = __builtin_amdgcn_mfma_f32_16x16x32_bf16(kf1, qf1, SVN[ct], 0, 0, 0); \
      }                                                                      \
      __builtin_amdgcn_s_setprio(0);                                         \
    }                                                                        \
    if ((mbits >> (s_ >> 1)) & 1) {                                          \
      _Pragma("unroll")                                                      \
      for (int ct = 0; ct < 4; ct++) {                                       \
        _Pragma("unroll")                                                    \
        for (int reg = 0; reg < 4; reg++) {                                  \
          const int kk = ((ct >> 1) << 5) + (quad << 3) + ((ct & 1) << 2) + reg; \
          size_t mi = (size_t)(q0 + lr) * 2048 + s_ * 64 + kk;               \
          float mv = mbf ? bf2f(((const unsigned short*)mask)[mi])           \
                         : ((const float*)mask)[mi];                         \
          SVC[ct][reg] -= 8e9f * mv;                                         \
        }                                                                    \
      }                                                                      \
    }                                                                        \
    float t_ = fmaxf(                                                        \
        fmaxf(fmaxf(fmaxf(SVC[0][0], SVC[0][1]), fmaxf(SVC[0][2], SVC[0][3])), \
              fmaxf(fmaxf(SVC[1][0], SVC[1][1]), fmaxf(SVC[1][2], SVC[1][3]))), \
        fmaxf(fmaxf(fmaxf(SVC[2][0], SVC[2][1]), fmaxf(SVC[2][2], SVC[2][3])), \
              fmaxf(fmaxf(SVC[3][0], SVC[3][1]), fmaxf(SVC[3][2], SVC[3][3])))); \
    t_ = fmaxf(t_, __shfl_xor(t_, 16));                                      \
    t_ = fmaxf(t_, __shfl_xor(t_, 32));                                      \
    if (__ballot(t_ > mrow + DEFER_THR)) {                                   \
      const float mnew = fmaxf(mrow, t_);                                    \
      const float alpha = fexp2((mrow - mnew) * SC2);                        \
      _Pragma("unroll")                                                      \
      for (int dt = 0; dt < 4; dt++) {                                       \
        _Pragma("unroll")                                                    \
        for (int reg = 0; reg < 4; reg++) ot[dt][reg] *= alpha;              \
      }                                                                      \
      lrow *= alpha;                                                         \
      mrow = mnew;                                                           \
    }                                                                        \
    const float mS = mrow * SC2;                                             \
    f16x8 pb8[2];                                                            \
    _Pragma("unroll")                                                        \
    for (int c2 = 0; c2 < 2; c2++) {                                         \
      union { hf2 hh[4]; f16x8 v; } u;                                       \
      _Pragma("unroll")                                                      \
      for (int hh2 = 0; hh2 < 2; hh2++) {                                    \
        const int ct = c2 * 2 + hh2;                                         \
        float p0 = fexp2(fmaf(SVC[ct][0], SC2, -mS));                        \
        float p1 = fexp2(fmaf(SVC[ct][1], SC2, -mS));                        \
        float p2 = fexp2(fmaf(SVC[ct][2], SC2, -mS));                        \
        float p3 = fexp2(fmaf(SVC[ct][3], SC2, -mS));                        \
        u.hh[hh2 * 2 + 0] = __builtin_amdgcn_cvt_pkrtz(p0, p1);              \
        u.hh[hh2 * 2 + 1] = __builtin_amdgcn_cvt_pkrtz(p2, p3);              \
      }                                                                      \
      pb8[c2] = u.v;                                                         \
    }                                                                        \
    const char* Vc = sm + 16384 + ((s_ & 1) << 13);                          \
    f32x4 asum = z;                                                          \
    __builtin_amdgcn_s_setprio(1);                                           \
    _Pragma("unroll")                                                        \
    for (int c2 = 0; c2 < 2; c2++) {                                         \
      const int vxo = c2 ? vxo1 : vxo0;                                      \
      asum = __builtin_amdgcn_mfma_f32_16x16x32_f16(ones8, pb8[c2], asum, 0, 0, 0); \
      _Pragma("unroll")                                                      \
      for (int dt = 0; dt < 4; dt++) {                                       \
        f16x8 va = *(const f16x8*)(Vc + (dt * 16 + lr) * 128 + vxo);         \
        ot[dt] = __builtin_amdgcn_mfma_f32_16x16x32_f16(va, pb8[c2], ot[dt], 0, 0, 0); \
      }                                                                      \
    }                                                                        \
    __builtin_amdgcn_s_setprio(0);                                           \
    lrow += asum[0];                                                         \
    if (s_ < 31) __syncthreads();                                            \
  }

  for (int s2 = 0; s2 < 32; s2 += 2) {
    FLASH_BODY(s2, svA, svB);
    FLASH_BODY(s2 + 1, svB, svA);
  }
#undef FLASH_BODY
#undef STAGE_K
#undef STAGE_V

  const float inv = 1.0f / lrow;
  bf16_t* arow = attn + ((size_t)bb * 2048 + q0 + lr) * 768 + h * 64 + g4;
#pragma unroll
  for (int dt = 0; dt < 4; dt++) {
    bf16x4 v;
#pragma unroll
    for (int reg = 0; reg < 4; reg++) v[reg] = (bf16_t)(ot[dt][reg] * inv);
    *(bf16x4*)(arow + dt * 16) = v;
  }
}

// -------------------------------------------------- output GEMM (attn @ Wo^T)
// Verified LDS version: 64x64 tiles -> 768 blocks (3/CU), BK=64
// double-buffered with prefetch-before-compute (two 32-k sub-tiles/slot).
// XCD-swizzled tile assignment (T1, 768%8==0): chunk of 96 tiles
// (8 m-panels x 12 n) per XCD -> A-panels HBM-fetched once.
__global__ __launch_bounds__(256, 3) void k_gemm2(
    const bf16_t* __restrict__ A, const bf16_t* __restrict__ Bm,
    const void* __restrict__ bo, const unsigned short* __restrict__ xdet,
    float* __restrict__ outF, unsigned short* __restrict__ outH) {
  __shared__ __align__(16) char smem[32768];  // A slots @0,8192 | B @16384,24576

  const int tid = threadIdx.x, wid = tid >> 6, lane = tid & 63;
  // T1 XCD swizzle: 768 blocks, chunk=96/XCD (bijective)
  const int lin = blockIdx.y * 12 + blockIdx.x;
  const int sw = (lin & 7) * 96 + (lin >> 3);
  const int n0 = (sw % 12) * 64, m0 = (sw / 12) * 64;
  const int wm = (wid >> 1) << 5, wn = (wid & 1) << 5;
  const int lr = lane & 15, lk = (lane >> 4) << 3, g4 = (lane >> 4) << 2;
  const bf16_t* Ag = A + (size_t)(m0 + (tid >> 2)) * 768 + ((tid & 3) << 3);
  const bf16_t* Bg = Bm + (size_t)(n0 + (tid >> 2)) * 768 + ((tid & 3) << 3);

  f32x4 acc[2][2];
  const f32x4 z = {0.f, 0.f, 0.f, 0.f};
#pragma unroll
  for (int i = 0; i < 2; i++)
#pragma unroll
    for (int j = 0; j < 2; j++) acc[i][j] = z;

  {  // stage k0=0 -> slot 0 (two 32-k halves per operand)
    bf16_t* A0 = (bf16_t*)smem;
    bf16_t* B0 = (bf16_t*)(smem + 16384);
    glds16(Ag, A0 + wid * 512);
    glds16(Ag + 32, A0 + 2048 + wid * 512);
    glds16(Bg, B0 + wid * 512);
    glds16(Bg + 32, B0 + 2048 + wid * 512);
  }
  __syncthreads();

  for (int s = 0; s < 12; s++) {
    if (s < 11) {  // prefetch s+1 into other slot
      const int k0 = (s + 1) * 64;
      bf16_t* An = (bf16_t*)(smem + ((s + 1) & 1) * 8192);
      bf16_t* Bn = (bf16_t*)(smem + 16384 + ((s + 1) & 1) * 8192);
      glds16(Ag + k0, An + wid * 512);
      glds16(Ag + k0 + 32, An + 2048 + wid * 512);
      glds16(Bg + k0, Bn + wid * 512);
      glds16(Bg + k0 + 32, Bn + 2048 + wid * 512);
    }
#pragma unroll
    for (int kc = 0; kc < 2; kc++) {
      const bf16_t* As = (const bf16_t*)(smem + (s & 1) * 8192) + kc * 2048;
      const bf16_t* Bs = (const bf16_t*)(smem + 16384 + (s & 1) * 8192) + kc * 2048;
      bf16x8 af[2], bf_[2];
#pragma unroll
      for (int i = 0; i < 2; i++) af[i]  = *(const bf16x8*)&As[(wm + i * 16 + lr) * 32 + lk];
#pragma unroll
      for (int j = 0; j < 2; j++) bf_[j] = *(const bf16x8*)&Bs[(wn + j * 16 + lr) * 32 + lk];
#pragma unroll
      for (int i = 0; i < 2; i++)
#pragma unroll
        for (int j = 0; j < 2; j++)
          acc[i][j] = __builtin_amdgcn_mfma_f32_16x16x32_bf16(af[i], bf_[j], acc[i][j], 0, 0, 0);
    }
    __syncthreads();
  }

  const int obf = detect_bf16_flag(xdet);
#pragma unroll
  for (int i = 0; i < 2; i++)
#pragma unroll
    for (int j = 0; j < 2; j++) {
      const int nn = n0 + wn + j * 16 + lr;
      const float bv = obf ? bf2f(((const unsigned short*)bo)[nn])
                           : ((const float*)bo)[nn];
#pragma unroll
      for (int reg = 0; reg < 4; reg++) {
        const int m = m0 + wm + i * 16 + g4 + reg;
        const float v = acc[i][j][reg] + bv;
        if (obf) outH[(size_t)m * 768 + nn] = __builtin_bit_cast(unsigned short, (bf16_t)v);
        else     outF[(size_t)m * 768 + nn] = v;
      }
    }
}

// -------------------------------------------------------------------- launch
extern "C" void kernel_launch(void* const* d_in, const int* in_sizes, int n_in,
                              void* d_out, int out_size, void* d_ws, size_t ws_size,
                              hipStream_t stream) {
  (void)in_sizes; (void)n_in; (void)out_size; (void)ws_size;
  const void* x    = d_in[0];
  const void* mask = d_in[1];
  const void* Wq   = d_in[2];
  const void* Wk   = d_in[3];
  const void* Wv   = d_in[4];
  const void* Wo   = d_in[5];
  const void* bo   = d_in[6];

  char* w = (char*)d_ws;
  size_t off = 0;
  auto take = [&](size_t b) -> void* {
    void* p = w + off;
    off = (off + b + 255) & ~(size_t)255;
    return p;
  };
  int*      mflags = (int*)take(256 * 4);
  bf16_t*   wqkvT  = (bf16_t*)take((size_t)2304 * 768 * 2);
  bf16_t*   woT    = (bf16_t*)take((size_t)768 * 768 * 2);
  bf16_t*   xb     = (bf16_t*)take((size_t)4096 * 768 * 2);
  bf16_t*   Qd     = (bf16_t*)take((size_t)3145728 * 2);
  char*     Kd     = (char*)take((size_t)3145728 * 2);
  char*     Vt     = (char*)take((size_t)3145728 * 2);
  bf16_t*   attn   = xb;  // xb dead after QKV GEMM (flash output reuses it)

  k_prep<<<4096, 256, 0, stream>>>(x, mask, Wq, Wk, Wv, Wo, xb, wqkvT, woT, mflags);
  k_gemmQKV<<<dim3(18, 32), 256, 0, stream>>>(xb, wqkvT, Qd, Kd, Vt,
                                              (const unsigned short*)x);
  k_flash<<<768, 256, 0, stream>>>(Qd, Kd, Vt, mask, mflags,
                                   (const unsigned short*)x, attn);
  k_gemm2<<<dim3(12, 64), 256, 0, stream>>>(attn, woT, bo, (const unsigned short*)x,
                                            (float*)d_out, (unsigned short*)d_out);
}